// Round 1
// baseline (274.719 us; speedup 1.0000x reference)
//
#include <hip/hip_runtime.h>

#define H 1024
#define E 64
#define BT 64
#define THETA 4e-4f    // relative p-gap risk threshold (widened for bf16-split path)

typedef __attribute__((ext_vector_type(4))) float f4;
typedef __attribute__((ext_vector_type(16))) float f32x16;
typedef __bf16 bf16x8 __attribute__((ext_vector_type(8)));
typedef unsigned int u32;
typedef __attribute__((ext_vector_type(4))) u32 u32x4;

__device__ __forceinline__ u32 cvtpk_bf16(float a, float b) {
    u32 r;
    asm("v_cvt_pk_bf16_f32 %0, %1, %2" : "=v"(r) : "v"(a), "v"(b));
    return r;
}
__device__ __forceinline__ float asfloat(u32 u) { union { u32 u; float f; } c; c.u = u; return c.f; }

// split 8 fp32 (k-ascending: a.xyzw, b.xyzw) into packed bf16-hi (RNE) and bf16-lo residual
__device__ __forceinline__ void split8(f4 a, f4 b, u32x4& hi, u32x4& lo) {
    float x0[4] = {a.x, a.z, b.x, b.z};
    float x1[4] = {a.y, a.w, b.y, b.w};
    #pragma unroll
    for (int i = 0; i < 4; ++i) {
        u32 h = cvtpk_bf16(x0[i], x1[i]);
        float r0 = x0[i] - asfloat(h << 16);
        float r1 = x1[i] - asfloat(h & 0xFFFF0000u);
        hi[i] = h;
        lo[i] = cvtpk_bf16(r0, r1);
    }
}

// =====================================================================
// Pass A: 64 tokens x 64 experts per block. Logits via split-bf16 MFMA
// (hi*hi into acc0; hi*lo + lo*hi into acc1), K-chunks of 64, double-
// buffered LDS (reg-staged fp32 -> bf16 hi/lo conversion, XOR-swizzled
// 16B slots so b128 reads/writes are conflict-free). Tail (softmax /
// top-8 / pi / hist / risk) unchanged from the pkfma version.
// LDS byte map per buffer b (b*32768): A_hi[64][64]bf16 @0, A_lo @8192,
//   B_hi @16384, B_lo @24576.
// tail (reuses buf0): S[64][68] @0, recip @f4352, hist @f4416, pi3 @f4480
// =====================================================================
__global__ __launch_bounds__(256, 2)
void gate_main(const float* __restrict__ hs, const float* __restrict__ wt,
               float* __restrict__ out, float* __restrict__ pi_ws,
               float* __restrict__ ce_ws, unsigned int* __restrict__ risk_cnt,
               unsigned int* __restrict__ risk_list, unsigned int risk_cap,
               int n_tokens) {
    __shared__ float smem[16384];                 // 64 KB
    const int t = threadIdx.x;
    const int wave = t >> 6, lane = t & 63;
    const int tok_base = blockIdx.x * BT;

    // ---- staging mapping: thread t owns rows (t>>3) and (t>>3)+32, k-pair jp=t&7
    const int srow = t >> 3;                      // 0..31
    const int sjp  = t & 7;
    const int ssw  = ((sjp ^ (srow & 7)) << 4);   // (srow+32)&7 == srow&7

    // ---- mfma mapping: wave (0..3) -> 32x32 output quadrant
    const int lr   = lane & 31;
    const int kh   = lane >> 5;
    const int wrow = (wave >> 1) * 32;            // token base of quadrant
    const int wcol = (wave & 1) * 32;             // expert base of quadrant
    const int aOff = (wrow + lr) * 128;           // A row byte offset
    const int bOff = 16384 + (wcol + lr) * 128;   // B row byte offset (hi tile)
    const int rsw  = lr & 7;

    f32x16 acc0, acc1;
    #pragma unroll
    for (int i = 0; i < 16; ++i) { acc0[i] = 0.f; acc1[i] = 0.f; }

    f4 sreg[8];
    char* sb = (char*)smem;

    auto stage_load = [&](int c) {
        const float* ph = hs + (size_t)(tok_base + srow) * H + c * 64 + sjp * 8;
        sreg[0] = *(const f4*)ph;
        sreg[1] = *(const f4*)(ph + 4);
        sreg[2] = *(const f4*)(ph + 32 * H);
        sreg[3] = *(const f4*)(ph + 32 * H + 4);
        const float* pw = wt + (size_t)srow * H + c * 64 + sjp * 8;
        sreg[4] = *(const f4*)pw;
        sreg[5] = *(const f4*)(pw + 4);
        sreg[6] = *(const f4*)(pw + 32 * H);
        sreg[7] = *(const f4*)(pw + 32 * H + 4);
    };
    auto stage_write = [&](int c) {
        char* bb = sb + (c & 1) * 32768;
        u32x4 hi, lo;
        split8(sreg[0], sreg[1], hi, lo);
        *(u32x4*)(bb + srow * 128 + ssw) = hi;
        *(u32x4*)(bb + 8192 + srow * 128 + ssw) = lo;
        split8(sreg[2], sreg[3], hi, lo);
        *(u32x4*)(bb + (srow + 32) * 128 + ssw) = hi;
        *(u32x4*)(bb + 8192 + (srow + 32) * 128 + ssw) = lo;
        split8(sreg[4], sreg[5], hi, lo);
        *(u32x4*)(bb + 16384 + srow * 128 + ssw) = hi;
        *(u32x4*)(bb + 24576 + srow * 128 + ssw) = lo;
        split8(sreg[6], sreg[7], hi, lo);
        *(u32x4*)(bb + 16384 + (srow + 32) * 128 + ssw) = hi;
        *(u32x4*)(bb + 24576 + (srow + 32) * 128 + ssw) = lo;
    };

    stage_load(0);
    stage_write(0);
    #pragma unroll 2
    for (int c = 0; c < 16; ++c) {
        __syncthreads();                          // buffer c ready
        if (c < 15) stage_load(c + 1);            // issue-early: HBM hides under MFMA
        const char* cb = sb + (c & 1) * 32768;
        #pragma unroll
        for (int kk = 0; kk < 4; ++kk) {
            const int g = ((kk * 2 + kh) ^ rsw) << 4;
            bf16x8 ah = *(const bf16x8*)(cb + aOff + g);
            bf16x8 al = *(const bf16x8*)(cb + 8192 + aOff + g);
            bf16x8 bh = *(const bf16x8*)(cb + bOff + g);
            bf16x8 bl = *(const bf16x8*)(cb + 8192 + bOff + g);
            acc0 = __builtin_amdgcn_mfma_f32_32x32x16_bf16(ah, bh, acc0, 0, 0, 0);
            acc1 = __builtin_amdgcn_mfma_f32_32x32x16_bf16(ah, bl, acc1, 0, 0, 0);
            acc1 = __builtin_amdgcn_mfma_f32_32x32x16_bf16(al, bh, acc1, 0, 0, 0);
        }
        __builtin_amdgcn_sched_barrier(0);        // keep vmcnt-wait+convert after MFMAs
        if (c < 15) stage_write(c + 1);           // write-late into buffer (c+1)&1
    }
    __syncthreads();

    // ---- fold split terms, write logits S[64][68] ----
    float* S = smem;
    f4* S4 = (f4*)smem;
    float* recip = smem + 4352;
    float* hist  = smem + 4416;
    float* pi3   = smem + 4480;
    {
        const int col = wcol + lr;                // expert
        #pragma unroll
        for (int gq = 0; gq < 4; ++gq)
            #pragma unroll
            for (int q = 0; q < 4; ++q) {
                const int row = wrow + gq * 8 + kh * 4 + q;   // token (C/D layout m74/m101)
                S[row * 68 + col] = acc0[gq * 4 + q] + acc1[gq * 4 + q];
            }
    }
    if (t < 64) hist[t] = 0.f;
    __syncthreads();

    // ---- p = exp(l - m) in-place, 4 threads per token ----
    {
        const int tok = t >> 2, q = t & 3;
        f4 v[4];
        #pragma unroll
        for (int c2 = 0; c2 < 4; ++c2) v[c2] = S4[tok * 17 + q * 4 + c2];
        float m = v[0].x;
        #pragma unroll
        for (int c2 = 0; c2 < 4; ++c2)
            m = fmaxf(m, fmaxf(fmaxf(v[c2].x, v[c2].y), fmaxf(v[c2].z, v[c2].w)));
        m = fmaxf(m, __shfl_xor(m, 1, 64));
        m = fmaxf(m, __shfl_xor(m, 2, 64));
        float lsum = 0.f;
        #pragma unroll
        for (int c2 = 0; c2 < 4; ++c2) {
            v[c2].x = __expf(v[c2].x - m); v[c2].y = __expf(v[c2].y - m);
            v[c2].z = __expf(v[c2].z - m); v[c2].w = __expf(v[c2].w - m);
            lsum += (v[c2].x + v[c2].y) + (v[c2].z + v[c2].w);
        }
        #pragma unroll
        for (int c2 = 0; c2 < 4; ++c2) S4[tok * 17 + q * 4 + c2] = v[c2];
        lsum += __shfl_xor(lsum, 1, 64);
        lsum += __shfl_xor(lsum, 2, 64);
        if (q == 0) recip[tok] = 1.0f / lsum;
    }
    __syncthreads();

    // ---- SEL (one wave, thread-per-token) + pi partials (other waves) ----
    const int selw = blockIdx.x & 3;
    if (wave == selw) {
        const int tok = lane;
        const int tok_g = tok_base + tok;
        float val[9]; int idx[9];
        #pragma unroll
        for (int r = 0; r < 9; ++r) { val[r] = -1.f; idx[r] = 0; }
        #pragma unroll
        for (int c2 = 0; c2 < 16; ++c2) {
            f4 v = S4[tok * 17 + c2];
            float e4[4] = {v.x, v.y, v.z, v.w};
            #pragma unroll
            for (int u = 0; u < 4; ++u) {
                float cv = e4[u]; int ci = c2 * 4 + u;
                #pragma unroll
                for (int r = 0; r < 9; ++r) {
                    const bool g = cv > val[r];    // strict: stream order = stable ties
                    const float tv = val[r]; const int ti = idx[r];
                    val[r] = g ? cv : tv;  idx[r] = g ? ci : ti;
                    cv = g ? tv : cv;      ci = g ? ti : ci;
                }
            }
        }
        const float s8 = ((val[0] + val[1]) + (val[2] + val[3]))
                       + ((val[4] + val[5]) + (val[6] + val[7]));
        const float wsum = s8 + 1e-20f;
        f4* out4 = (f4*)out;
        f4 o;
        o.x = (float)idx[0]; o.y = (float)idx[1]; o.z = (float)idx[2]; o.w = (float)idx[3];
        out4[(size_t)tok_g * 2] = o;
        o.x = (float)idx[4]; o.y = (float)idx[5]; o.z = (float)idx[6]; o.w = (float)idx[7];
        out4[(size_t)tok_g * 2 + 1] = o;
        const size_t wb = (size_t)n_tokens * 2;
        o.x = val[0] / wsum; o.y = val[1] / wsum; o.z = val[2] / wsum; o.w = val[3] / wsum;
        out4[wb + (size_t)tok_g * 2] = o;
        o.x = val[4] / wsum; o.y = val[5] / wsum; o.z = val[6] / wsum; o.w = val[7] / wsum;
        out4[wb + (size_t)tok_g * 2 + 1] = o;
        #pragma unroll
        for (int r = 0; r < 8; ++r) atomicAdd(&hist[idx[r]], 1.0f);
        float ming = 1e30f;
        #pragma unroll
        for (int r = 0; r < 8; ++r)
            ming = fminf(ming, (val[r] - val[r + 1]) / fmaxf(val[r], 1e-30f));
        if (ming < THETA) {
            unsigned int pos = atomicAdd(risk_cnt, 1u);
            if (pos < risk_cap) risk_list[pos] = (unsigned int)tok_g;
        }
    } else {
        const int third = ((wave - selw) & 3) - 1;        // 0..2
        const int e = lane;
        const int t0 = third * 21;
        const int t1 = (third == 2) ? 64 : (t0 + 21);
        float part = 0.f;
        for (int tok = t0; tok < t1; ++tok)
            part = fmaf(S[tok * 68 + e], recip[tok], part);
        pi3[third * 64 + e] = part;
    }
    __syncthreads();
    if (t < 64)       atomicAdd(&pi_ws[t], pi3[t] + pi3[64 + t] + pi3[128 + t]);
    else if (t < 128) atomicAdd(&ce_ws[t - 64], hist[t - 64]);
}

// =====================================================================
// Pass B: fp64 recompute of risky tokens (exact ranking); block 0 also
// finalizes the aux loss (pi/ce complete at kernel boundary).
// =====================================================================
__global__ __launch_bounds__(256)
void gate_fixup(const float* __restrict__ hs, const float* __restrict__ wt,
                float* __restrict__ out, const unsigned int* __restrict__ risk_cnt,
                const unsigned int* __restrict__ risk_list, unsigned int risk_cap,
                int n_tokens, const float* __restrict__ pi_ws,
                const float* __restrict__ ce_ws) {
    __shared__ float hrow[H];
    __shared__ double red[256];
    const int t = threadIdx.x;

    if (blockIdx.x == 0 && t < 64) {              // aux loss (wave 0 only)
        double pi = (double)pi_ws[t] / (double)n_tokens;
        double ce = (double)ce_ws[t] / ((double)n_tokens * 8.0);
        double term = pi * ce * 64.0;
        #pragma unroll
        for (int off = 32; off > 0; off >>= 1) term += __shfl_xor(term, off, 64);
        if (t == 0) out[(size_t)n_tokens * 16] = (float)(term * 0.01);
    }

    unsigned int cnt = *risk_cnt;
    if (cnt > risk_cap) cnt = risk_cap;

    for (unsigned int u = blockIdx.x; u < cnt; u += gridDim.x) {
        const int tok = (int)risk_list[u];
        ((float4*)hrow)[t] = ((const float4*)(hs + (size_t)tok * H))[t];
        __syncthreads();

        const int e = t >> 2, sl = t & 3;
        const float4* wp = (const float4*)wt + (size_t)e * 256;
        const float4* hp = (const float4*)hrow;
        double acc = 0.0;
        #pragma unroll 8
        for (int k4 = 0; k4 < 64; ++k4) {
            float4 wv = wp[k4 * 4 + sl];
            float4 hv = hp[k4 * 4 + sl];
            acc = fma((double)wv.x, (double)hv.x, acc);
            acc = fma((double)wv.y, (double)hv.y, acc);
            acc = fma((double)wv.z, (double)hv.z, acc);
            acc = fma((double)wv.w, (double)hv.w, acc);
        }
        red[t] = acc;
        __syncthreads();

        if (t < 64) {
            const int lane = t;
            double lg = red[t * 4] + red[t * 4 + 1] + red[t * 4 + 2] + red[t * 4 + 3];
            double m = lg;
            #pragma unroll
            for (int off = 32; off > 0; off >>= 1) {
                double o = __shfl_xor(m, off, 64);
                m = (o > m) ? o : m;
            }
            const double p = exp(lg - m);
            double v = lg, psum = 0.0, mypv = 0.0;
            int myidx = 0;
            for (int r = 0; r < 8; ++r) {
                double bv = v; int bi = lane;
                #pragma unroll
                for (int off = 32; off > 0; off >>= 1) {
                    double ov = __shfl_xor(bv, off, 64);
                    int    oi = __shfl_xor(bi, off, 64);
                    if (ov > bv || (ov == bv && oi < bi)) { bv = ov; bi = oi; }
                }
                double pw = __shfl(p, bi, 64);
                psum += pw;
                if (lane == r) { myidx = bi; mypv = pw; }
                if (lane == bi) v = -1e300;
            }
            const double wsum = psum + 1e-20;
            if (lane < 8) {
                out[(size_t)tok * 8 + lane] = (float)myidx;
                out[(size_t)n_tokens * 8 + (size_t)tok * 8 + lane] = (float)(mypv / wsum);
            }
        }
        __syncthreads();
    }
}

extern "C" void kernel_launch(void* const* d_in, const int* in_sizes, int n_in,
                              void* d_out, int out_size, void* d_ws, size_t ws_size,
                              hipStream_t stream) {
    const float* hs = (const float*)d_in[0];
    const float* wt = (const float*)d_in[1];
    float* out = (float*)d_out;
    const int n_tokens = in_sizes[0] / H;         // 32768

    float* pi_ws = (float*)d_ws;
    float* ce_ws = (float*)((char*)d_ws + 256);
    unsigned int* risk_cnt  = (unsigned int*)((char*)d_ws + 512);
    unsigned int* risk_list = (unsigned int*)((char*)d_ws + 1024);
    unsigned int risk_cap = (unsigned int)((ws_size > 1024 ? (ws_size - 1024) : 0) / 4);
    if (risk_cap > (unsigned int)n_tokens) risk_cap = (unsigned int)n_tokens;

    size_t zbytes = ws_size < 1024 ? ws_size : 1024;
    hipMemsetAsync(d_ws, 0, zbytes, stream);

    gate_main<<<n_tokens / BT, 256, 0, stream>>>(hs, wt, out, pi_ws, ce_ws,
                                                 risk_cnt, risk_list, risk_cap, n_tokens);
    gate_fixup<<<256, 256, 0, stream>>>(hs, wt, out, risk_cnt, risk_list, risk_cap,
                                        n_tokens, pi_ws, ce_ws);
}

// Round 2
// 251.445 us; speedup vs baseline: 1.0926x; 1.0926x over previous
//
#include <hip/hip_runtime.h>

#define H 1024
#define E 64
#define BT 64
#define THETA 2e-4f    // relative p-gap risk threshold (~7x margin over split-bf16 error tail)

typedef __attribute__((ext_vector_type(4))) float f4;
typedef __attribute__((ext_vector_type(16))) float f32x16;
typedef __bf16 bf16x8 __attribute__((ext_vector_type(8)));
typedef unsigned int u32;
typedef __attribute__((ext_vector_type(4))) u32 u32x4;

__device__ __forceinline__ u32 cvtpk_bf16(float a, float b) {
    u32 r;
    asm("v_cvt_pk_bf16_f32 %0, %1, %2" : "=v"(r) : "v"(a), "v"(b));
    return r;
}
__device__ __forceinline__ float asfloat(u32 u) { union { u32 u; float f; } c; c.u = u; return c.f; }

// split 8 fp32 (k-ascending: a.xyzw, b.xyzw) into packed bf16-hi (RNE) and bf16-lo residual
__device__ __forceinline__ void split8(f4 a, f4 b, u32x4& hi, u32x4& lo) {
    float x0[4] = {a.x, a.z, b.x, b.z};
    float x1[4] = {a.y, a.w, b.y, b.w};
    #pragma unroll
    for (int i = 0; i < 4; ++i) {
        u32 h = cvtpk_bf16(x0[i], x1[i]);
        float r0 = x0[i] - asfloat(h << 16);
        float r1 = x1[i] - asfloat(h & 0xFFFF0000u);
        hi[i] = h;
        lo[i] = cvtpk_bf16(r0, r1);
    }
}

// async global->LDS, 16B per lane; LDS dest = wave-uniform base + lane*16
__device__ __forceinline__ void async16(const void* g, void* l) {
    __builtin_amdgcn_global_load_lds(
        (const __attribute__((address_space(1))) unsigned int*)g,
        (__attribute__((address_space(3))) unsigned int*)l,
        16, 0, 0);
}

// =====================================================================
// Pass A: 64 tokens x 64 experts per block, 512 threads = 8 waves
// (4 output quadrants x 2 K-halves -> 16 waves/CU at 2 blocks/CU).
// Staging: global_load_lds of RAW fp32 tiles (A[64][64], B[64][64] per
// 64-K chunk), double-buffered; source-side XOR swizzle (col f4-slot
// j ^= row&7) so swizzled b128 fragment reads are bank-conflict-free.
// hi/lo bf16 split happens at fragment-read time; 3 MFMA per 16-K slice
// (hi*hi -> acc0, hi*lo + lo*hi -> acc1). K-half partials combined via
// LDS (P2) before the softmax/top-8/pi/hist tail.
// LDS float map: buf0 A[0,4096) B[4096,8192) | buf1 A[8192,12288) B[12288,16384)
// tail (reuses both): S[64][68] @0, P2[4][32][32] @4352, recip @8448,
//   hist @8512, pi7[7][64] @8576
// =====================================================================
__global__ __launch_bounds__(512, 4)
void gate_main(const float* __restrict__ hs, const float* __restrict__ wt,
               float* __restrict__ out, float* __restrict__ pi_ws,
               float* __restrict__ ce_ws, unsigned int* __restrict__ risk_cnt,
               unsigned int* __restrict__ risk_list, unsigned int risk_cap,
               int n_tokens) {
    __shared__ float smem[16384];                 // 64 KB
    const int t = threadIdx.x;
    const int wave = t >> 6, lane = t & 63;
    const int tok_base = blockIdx.x * BT;

    const int lr  = lane & 31;
    const int kh  = lane >> 5;
    const int q4  = wave & 3;                     // output quadrant
    const int kh2 = wave >> 2;                    // K-half of each chunk
    const int wrow = (q4 >> 1) * 32;              // token base of quadrant
    const int wcol = (q4 & 1) * 32;               // expert base of quadrant

    f32x16 acc0, acc1;
    #pragma unroll
    for (int i = 0; i < 16; ++i) { acc0[i] = 0.f; acc1[i] = 0.f; }

    char* sb = (char*)smem;

    // stage chunk c (64 K) into buffer b: 4 x global_load_lds dwordx4 per thread
    auto stage = [&](int c, int b) {
        char* bb = sb + b * 32768;
        #pragma unroll
        for (int q = 0; q < 4; ++q) {             // q<2: A tile, q>=2: B tile
            const int L = q * 512 + t;            // f4 linear index in [0,2048)
            const int r = (L >> 4) & 63;          // row within tile
            const int j = L & 15;
            const int srcj = j ^ (r & 7);         // source-side swizzle
            const float* src = (q < 2)
                ? hs + (size_t)(tok_base + r) * H + c * 64 + srcj * 4
                : wt + (size_t)r * H + c * 64 + srcj * 4;
            async16(src, bb + ((q * 512 + wave * 64) << 4));
        }
    };

    stage(0, 0);
    const int arow = wrow + lr;                   // token row this lane reads
    const int brow = wcol + lr;                   // expert row this lane reads
    const int abase = arow * 256;                 // byte offsets in buffer
    const int bbase = 16384 + brow * 256;
    const int asw = arow & 7, bsw = brow & 7;

    #pragma unroll 2
    for (int c = 0; c < 16; ++c) {
        __syncthreads();                          // drains vmcnt: buffer c ready
        if (c < 15) stage(c + 1, (c + 1) & 1);
        const char* cb = sb + (c & 1) * 32768;
        #pragma unroll
        for (int ks = 0; ks < 2; ++ks) {
            const int s = kh2 * 8 + ks * 4 + kh * 2;   // f4 slot of this 8-f32 frag
            f4 a0 = *(const f4*)(cb + abase + ((s ^ asw) << 4));
            f4 a1 = *(const f4*)(cb + abase + (((s + 1) ^ asw) << 4));
            f4 b0 = *(const f4*)(cb + bbase + ((s ^ bsw) << 4));
            f4 b1 = *(const f4*)(cb + bbase + (((s + 1) ^ bsw) << 4));
            u32x4 ahp, alp, bhp, blp;
            split8(a0, a1, ahp, alp);
            split8(b0, b1, bhp, blp);
            const bf16x8 ah = __builtin_bit_cast(bf16x8, ahp);
            const bf16x8 al = __builtin_bit_cast(bf16x8, alp);
            const bf16x8 bh = __builtin_bit_cast(bf16x8, bhp);
            const bf16x8 bl = __builtin_bit_cast(bf16x8, blp);
            acc0 = __builtin_amdgcn_mfma_f32_32x32x16_bf16(ah, bh, acc0, 0, 0, 0);
            acc1 = __builtin_amdgcn_mfma_f32_32x32x16_bf16(ah, bl, acc1, 0, 0, 0);
            acc1 = __builtin_amdgcn_mfma_f32_32x32x16_bf16(al, bh, acc1, 0, 0, 0);
        }
    }
    __syncthreads();                              // buffers dead from here

    float* S = smem;
    f4* S4 = (f4*)smem;
    float* P2    = smem + 4352;                   // [4][32][32] K-half partials
    float* recip = smem + 8448;
    float* hist  = smem + 8512;
    float* pi7   = smem + 8576;                   // [7][64]

    // ---- combine K-half partials, write logits S[64][68] ----
    {
        float vs[16];
        #pragma unroll
        for (int i = 0; i < 16; ++i) vs[i] = acc0[i] + acc1[i];
        if (kh2) {
            #pragma unroll
            for (int gq = 0; gq < 4; ++gq)
                #pragma unroll
                for (int qq = 0; qq < 4; ++qq)
                    P2[q4 * 1024 + (qq + gq * 8 + kh * 4) * 32 + lr] = vs[gq * 4 + qq];
        }
        if (t < 64) hist[t] = 0.f;
        __syncthreads();
        if (!kh2) {
            #pragma unroll
            for (int gq = 0; gq < 4; ++gq)
                #pragma unroll
                for (int qq = 0; qq < 4; ++qq) {
                    const int row = qq + gq * 8 + kh * 4;   // C/D layout (m74/m101)
                    S[(wrow + row) * 68 + wcol + lr] =
                        vs[gq * 4 + qq] + P2[q4 * 1024 + row * 32 + lr];
                }
        }
    }
    __syncthreads();

    // ---- p = exp(l - m) in-place, 4 threads per token (threads 0..255) ----
    if (t < 256) {
        const int tok = t >> 2, q = t & 3;
        f4 v[4];
        #pragma unroll
        for (int c2 = 0; c2 < 4; ++c2) v[c2] = S4[tok * 17 + q * 4 + c2];
        float m = v[0].x;
        #pragma unroll
        for (int c2 = 0; c2 < 4; ++c2)
            m = fmaxf(m, fmaxf(fmaxf(v[c2].x, v[c2].y), fmaxf(v[c2].z, v[c2].w)));
        m = fmaxf(m, __shfl_xor(m, 1, 64));
        m = fmaxf(m, __shfl_xor(m, 2, 64));
        float lsum = 0.f;
        #pragma unroll
        for (int c2 = 0; c2 < 4; ++c2) {
            v[c2].x = __expf(v[c2].x - m); v[c2].y = __expf(v[c2].y - m);
            v[c2].z = __expf(v[c2].z - m); v[c2].w = __expf(v[c2].w - m);
            lsum += (v[c2].x + v[c2].y) + (v[c2].z + v[c2].w);
        }
        #pragma unroll
        for (int c2 = 0; c2 < 4; ++c2) S4[tok * 17 + q * 4 + c2] = v[c2];
        lsum += __shfl_xor(lsum, 1, 64);
        lsum += __shfl_xor(lsum, 2, 64);
        if (q == 0) recip[tok] = 1.0f / lsum;
    }
    __syncthreads();

    // ---- SEL (one wave, thread-per-token) + pi partials (other 7 waves) ----
    const int selw = blockIdx.x & 7;
    if (wave == selw) {
        const int tok = lane;
        const int tok_g = tok_base + tok;
        float val[9]; int idx[9];
        #pragma unroll
        for (int r = 0; r < 9; ++r) { val[r] = -1.f; idx[r] = 0; }
        #pragma unroll
        for (int c2 = 0; c2 < 16; ++c2) {
            f4 v = S4[tok * 17 + c2];
            float e4[4] = {v.x, v.y, v.z, v.w};
            #pragma unroll
            for (int u = 0; u < 4; ++u) {
                float cv = e4[u]; int ci = c2 * 4 + u;
                #pragma unroll
                for (int r = 0; r < 9; ++r) {
                    const bool g = cv > val[r];    // strict: stream order = stable ties
                    const float tv = val[r]; const int ti = idx[r];
                    val[r] = g ? cv : tv;  idx[r] = g ? ci : ti;
                    cv = g ? tv : cv;      ci = g ? ti : ci;
                }
            }
        }
        const float s8 = ((val[0] + val[1]) + (val[2] + val[3]))
                       + ((val[4] + val[5]) + (val[6] + val[7]));
        const float wsum = s8 + 1e-20f;
        f4* out4 = (f4*)out;
        f4 o;
        o.x = (float)idx[0]; o.y = (float)idx[1]; o.z = (float)idx[2]; o.w = (float)idx[3];
        out4[(size_t)tok_g * 2] = o;
        o.x = (float)idx[4]; o.y = (float)idx[5]; o.z = (float)idx[6]; o.w = (float)idx[7];
        out4[(size_t)tok_g * 2 + 1] = o;
        const size_t wb = (size_t)n_tokens * 2;
        o.x = val[0] / wsum; o.y = val[1] / wsum; o.z = val[2] / wsum; o.w = val[3] / wsum;
        out4[wb + (size_t)tok_g * 2] = o;
        o.x = val[4] / wsum; o.y = val[5] / wsum; o.z = val[6] / wsum; o.w = val[7] / wsum;
        out4[wb + (size_t)tok_g * 2 + 1] = o;
        #pragma unroll
        for (int r = 0; r < 8; ++r) atomicAdd(&hist[idx[r]], 1.0f);
        float ming = 1e30f;
        #pragma unroll
        for (int r = 0; r < 8; ++r)
            ming = fminf(ming, (val[r] - val[r + 1]) / fmaxf(val[r], 1e-30f));
        if (ming < THETA) {
            unsigned int pos = atomicAdd(risk_cnt, 1u);
            if (pos < risk_cap) risk_list[pos] = (unsigned int)tok_g;
        }
    } else {
        const int sev = ((wave - selw) & 7) - 1;          // 0..6
        const int e = lane;
        const int t0 = sev * 9;
        const int t1 = (sev == 6) ? 64 : (t0 + 9);
        float part = 0.f;
        for (int tok = t0; tok < t1; ++tok)
            part = fmaf(S[tok * 68 + e], recip[tok], part);
        pi7[sev * 64 + e] = part;
    }
    __syncthreads();
    if (t < 64) {
        const float p = ((pi7[t] + pi7[64 + t]) + (pi7[128 + t] + pi7[192 + t]))
                      + ((pi7[256 + t] + pi7[320 + t]) + pi7[384 + t]);
        atomicAdd(&pi_ws[t], p);
    } else if (t < 128) {
        atomicAdd(&ce_ws[t - 64], hist[t - 64]);
    }
}

// =====================================================================
// Pass B: fp64 recompute of risky tokens (exact ranking); block 0 also
// finalizes the aux loss (pi/ce complete at kernel boundary).
// =====================================================================
__global__ __launch_bounds__(256)
void gate_fixup(const float* __restrict__ hs, const float* __restrict__ wt,
                float* __restrict__ out, const unsigned int* __restrict__ risk_cnt,
                const unsigned int* __restrict__ risk_list, unsigned int risk_cap,
                int n_tokens, const float* __restrict__ pi_ws,
                const float* __restrict__ ce_ws) {
    __shared__ float hrow[H];
    __shared__ double red[256];
    const int t = threadIdx.x;

    if (blockIdx.x == 0 && t < 64) {              // aux loss (wave 0 only)
        double pi = (double)pi_ws[t] / (double)n_tokens;
        double ce = (double)ce_ws[t] / ((double)n_tokens * 8.0);
        double term = pi * ce * 64.0;
        #pragma unroll
        for (int off = 32; off > 0; off >>= 1) term += __shfl_xor(term, off, 64);
        if (t == 0) out[(size_t)n_tokens * 16] = (float)(term * 0.01);
    }

    unsigned int cnt = *risk_cnt;
    if (cnt > risk_cap) cnt = risk_cap;

    for (unsigned int u = blockIdx.x; u < cnt; u += gridDim.x) {
        const int tok = (int)risk_list[u];
        ((float4*)hrow)[t] = ((const float4*)(hs + (size_t)tok * H))[t];
        __syncthreads();

        const int e = t >> 2, sl = t & 3;
        const float4* wp = (const float4*)wt + (size_t)e * 256;
        const float4* hp = (const float4*)hrow;
        double acc = 0.0;
        #pragma unroll 8
        for (int k4 = 0; k4 < 64; ++k4) {
            float4 wv = wp[k4 * 4 + sl];
            float4 hv = hp[k4 * 4 + sl];
            acc = fma((double)wv.x, (double)hv.x, acc);
            acc = fma((double)wv.y, (double)hv.y, acc);
            acc = fma((double)wv.z, (double)hv.z, acc);
            acc = fma((double)wv.w, (double)hv.w, acc);
        }
        red[t] = acc;
        __syncthreads();

        if (t < 64) {
            const int lane = t;
            double lg = red[t * 4] + red[t * 4 + 1] + red[t * 4 + 2] + red[t * 4 + 3];
            double m = lg;
            #pragma unroll
            for (int off = 32; off > 0; off >>= 1) {
                double o = __shfl_xor(m, off, 64);
                m = (o > m) ? o : m;
            }
            const double p = exp(lg - m);
            double v = lg, psum = 0.0, mypv = 0.0;
            int myidx = 0;
            for (int r = 0; r < 8; ++r) {
                double bv = v; int bi = lane;
                #pragma unroll
                for (int off = 32; off > 0; off >>= 1) {
                    double ov = __shfl_xor(bv, off, 64);
                    int    oi = __shfl_xor(bi, off, 64);
                    if (ov > bv || (ov == bv && oi < bi)) { bv = ov; bi = oi; }
                }
                double pw = __shfl(p, bi, 64);
                psum += pw;
                if (lane == r) { myidx = bi; mypv = pw; }
                if (lane == bi) v = -1e300;
            }
            const double wsum = psum + 1e-20;
            if (lane < 8) {
                out[(size_t)tok * 8 + lane] = (float)myidx;
                out[(size_t)n_tokens * 8 + (size_t)tok * 8 + lane] = (float)(mypv / wsum);
            }
        }
        __syncthreads();
    }
}

extern "C" void kernel_launch(void* const* d_in, const int* in_sizes, int n_in,
                              void* d_out, int out_size, void* d_ws, size_t ws_size,
                              hipStream_t stream) {
    const float* hs = (const float*)d_in[0];
    const float* wt = (const float*)d_in[1];
    float* out = (float*)d_out;
    const int n_tokens = in_sizes[0] / H;         // 32768

    float* pi_ws = (float*)d_ws;
    float* ce_ws = (float*)((char*)d_ws + 256);
    unsigned int* risk_cnt  = (unsigned int*)((char*)d_ws + 512);
    unsigned int* risk_list = (unsigned int*)((char*)d_ws + 1024);
    unsigned int risk_cap = (unsigned int)((ws_size > 1024 ? (ws_size - 1024) : 0) / 4);
    if (risk_cap > (unsigned int)n_tokens) risk_cap = (unsigned int)n_tokens;

    size_t zbytes = ws_size < 1024 ? ws_size : 1024;
    hipMemsetAsync(d_ws, 0, zbytes, stream);

    gate_main<<<n_tokens / BT, 512, 0, stream>>>(hs, wt, out, pi_ws, ce_ws,
                                                 risk_cnt, risk_list, risk_cap, n_tokens);
    gate_fixup<<<256, 256, 0, stream>>>(hs, wt, out, risk_cnt, risk_list, risk_cap,
                                        n_tokens, pi_ws, ce_ws);
}

// Round 4
// 238.501 us; speedup vs baseline: 1.1519x; 1.0543x over previous
//
#include <hip/hip_runtime.h>

#define H 1024
#define E 64
#define BT 64
#define THETA 2e-4f    // relative p-gap risk threshold (~7x margin over split-bf16 error tail)

typedef __attribute__((ext_vector_type(4))) float f4;
typedef __attribute__((ext_vector_type(16))) float f32x16;
typedef __bf16 bf16x8 __attribute__((ext_vector_type(8)));
typedef unsigned int u32;
typedef __attribute__((ext_vector_type(4))) u32 u32x4;

__device__ __forceinline__ u32 cvtpk_bf16(float a, float b) {
    u32 r;
    asm("v_cvt_pk_bf16_f32 %0, %1, %2" : "=v"(r) : "v"(a), "v"(b));
    return r;
}
__device__ __forceinline__ float asfloat(u32 u) { union { u32 u; float f; } c; c.u = u; return c.f; }

// split 8 fp32 (k-ascending: a.xyzw, b.xyzw) into packed bf16-hi (RNE) and bf16-lo residual
__device__ __forceinline__ void split8(f4 a, f4 b, u32x4& hi, u32x4& lo) {
    float x0[4] = {a.x, a.z, b.x, b.z};
    float x1[4] = {a.y, a.w, b.y, b.w};
    #pragma unroll
    for (int i = 0; i < 4; ++i) {
        u32 h = cvtpk_bf16(x0[i], x1[i]);
        float r0 = x0[i] - asfloat(h << 16);
        float r1 = x1[i] - asfloat(h & 0xFFFF0000u);
        hi[i] = h;
        lo[i] = cvtpk_bf16(r0, r1);
    }
}

// async global->LDS, 16B per lane; LDS dest = wave-uniform base + lane*16
__device__ __forceinline__ void async16(const void* g, void* l) {
    __builtin_amdgcn_global_load_lds(
        (const __attribute__((address_space(1))) unsigned int*)g,
        (__attribute__((address_space(3))) unsigned int*)l,
        16, 0, 0);
}

// =====================================================================
// Pass A: 64 tokens x 64 experts per block, 512 threads = 8 waves
// (4 output quadrants x 2 K-halves). Counted-vmcnt pipeline (T3/T4):
// K-chunks of 32, FOUR 16 KB LDS buffers, prefetch depth 3, raw
// s_barrier + "s_waitcnt vmcnt(4)" per chunk — vmcnt NEVER drains to 0
// in the main loop, so global_load_lds stays in flight across barriers.
// Source-side XOR swizzle (f4-slot j ^= row&7) keeps b128 fragment
// reads bank-conflict-free; split-bf16 MFMA math unchanged (3 MFMA per
// 16-K step: hi*hi -> acc0, hi*lo + lo*hi -> acc1).
// LDS byte map: buf b at b*16384: A[64][32]f32 @0, B @8192.
// tail (reuses bufs): S[64][68] @f0, P2[4][32][32] @f4352, recip @f8448,
//   hist @f8512, pi7[7][64] @f8576
// (resubmission of round-3 source: container-level failure, no defect
//  found in hang/fault audit — barriers uniform, vmcnt protocol sound,
//  buffer reuse follows the verified m201 discipline, addresses bounded)
// =====================================================================
__global__ __launch_bounds__(512, 4)
void gate_main(const float* __restrict__ hs, const float* __restrict__ wt,
               float* __restrict__ out, float* __restrict__ pi_ws,
               float* __restrict__ ce_ws, unsigned int* __restrict__ risk_cnt,
               unsigned int* __restrict__ risk_list, unsigned int risk_cap,
               int n_tokens) {
    __shared__ float smem[16384];                 // 64 KB
    const int t = threadIdx.x;
    const int wave = t >> 6, lane = t & 63;
    const int tok_base = blockIdx.x * BT;
    char* sb = (char*)smem;

    // ---- staging constants: thread t owns row t>>3, k-slot (t&7), swizzled source
    const int srow = t >> 3;                      // 0..63
    const int srcj = (t & 7) ^ (srow & 7);
    const float* gA = hs + (size_t)(tok_base + srow) * H + srcj * 4;
    const float* gB = wt + (size_t)srow * H + srcj * 4;
    const int sdest = wave << 10;                 // wave-uniform LDS base (bytes)

    // ---- mfma constants: wave -> quadrant (q4) x K-half (kh2)
    const int lr = lane & 31, kh = lane >> 5;
    const int q4 = wave & 3, kh2 = wave >> 2;
    const int wrow = (q4 >> 1) * 32;              // token base of quadrant
    const int wcol = (q4 & 1) * 32;               // expert base of quadrant
    const int arow = wrow + lr, brow = wcol + lr;
    const int s0 = kh2 * 4 + kh * 2;              // even f4 slot of this lane's 8 k
    const int aoff = arow * 128 + ((s0 ^ (arow & 7)) << 4);
    const int boff = 8192 + brow * 128 + ((s0 ^ (brow & 7)) << 4);

    f32x16 acc0, acc1;
    #pragma unroll
    for (int i = 0; i < 16; ++i) { acc0[i] = 0.f; acc1[i] = 0.f; }

    auto stage = [&](int c) {                     // 2 async16 per thread
        char* bb = sb + (c & 3) * 16384;
        async16(gA + c * 32, bb + sdest);
        async16(gB + c * 32, bb + 8192 + sdest);
    };
    auto compute = [&](int c) {                   // one 16-K MFMA step per wave
        const char* cb = sb + (c & 3) * 16384;
        f4 a0 = *(const f4*)(cb + aoff);
        f4 a1 = *(const f4*)(cb + (aoff ^ 16));
        f4 b0 = *(const f4*)(cb + boff);
        f4 b1 = *(const f4*)(cb + (boff ^ 16));
        u32x4 ahp, alp, bhp, blp;
        split8(a0, a1, ahp, alp);
        split8(b0, b1, bhp, blp);
        const bf16x8 ah = __builtin_bit_cast(bf16x8, ahp);
        const bf16x8 al = __builtin_bit_cast(bf16x8, alp);
        const bf16x8 bh = __builtin_bit_cast(bf16x8, bhp);
        const bf16x8 bl = __builtin_bit_cast(bf16x8, blp);
        acc0 = __builtin_amdgcn_mfma_f32_32x32x16_bf16(ah, bh, acc0, 0, 0, 0);
        acc1 = __builtin_amdgcn_mfma_f32_32x32x16_bf16(ah, bl, acc1, 0, 0, 0);
        acc1 = __builtin_amdgcn_mfma_f32_32x32x16_bf16(al, bh, acc1, 0, 0, 0);
    };

    // ---- prologue: 3 chunks in flight (6 loads/thread)
    stage(0); stage(1); stage(2);
    // ---- main loop: wait own-oldest only (4 = chunks c+1,c+2 in flight)
    for (int c = 0; c < 30; ++c) {
        asm volatile("s_waitcnt vmcnt(4)" ::: "memory");
        __builtin_amdgcn_s_barrier();             // publish chunk c; frees buf (c-1)&3
        __builtin_amdgcn_sched_barrier(0);
        if (c < 29) stage(c + 3);
        __builtin_amdgcn_sched_barrier(0);        // pin loads before compute
        compute(c);
    }
    asm volatile("s_waitcnt vmcnt(2)" ::: "memory");
    __builtin_amdgcn_s_barrier();
    __builtin_amdgcn_sched_barrier(0);
    compute(30);
    asm volatile("s_waitcnt vmcnt(0)" ::: "memory");
    __builtin_amdgcn_s_barrier();
    __builtin_amdgcn_sched_barrier(0);
    compute(31);
    __syncthreads();                              // full drain; buffers dead

    float* S = smem;
    f4* S4 = (f4*)smem;
    float* P2    = smem + 4352;                   // [4][32][32] K-half partials
    float* recip = smem + 8448;
    float* hist  = smem + 8512;
    float* pi7   = smem + 8576;                   // [7][64]

    // ---- combine K-half partials, write logits S[64][68] ----
    {
        float vs[16];
        #pragma unroll
        for (int i = 0; i < 16; ++i) vs[i] = acc0[i] + acc1[i];
        if (kh2) {
            #pragma unroll
            for (int gq = 0; gq < 4; ++gq)
                #pragma unroll
                for (int qq = 0; qq < 4; ++qq)
                    P2[q4 * 1024 + (qq + gq * 8 + kh * 4) * 32 + lr] = vs[gq * 4 + qq];
        }
        if (t < 64) hist[t] = 0.f;
        __syncthreads();
        if (!kh2) {
            #pragma unroll
            for (int gq = 0; gq < 4; ++gq)
                #pragma unroll
                for (int qq = 0; qq < 4; ++qq) {
                    const int row = qq + gq * 8 + kh * 4;   // C/D layout (m74/m101)
                    S[(wrow + row) * 68 + wcol + lr] =
                        vs[gq * 4 + qq] + P2[q4 * 1024 + row * 32 + lr];
                }
        }
    }
    __syncthreads();

    // ---- p = exp(l - m) in-place, 4 threads per token (threads 0..255) ----
    if (t < 256) {
        const int tok = t >> 2, q = t & 3;
        f4 v[4];
        #pragma unroll
        for (int c2 = 0; c2 < 4; ++c2) v[c2] = S4[tok * 17 + q * 4 + c2];
        float m = v[0].x;
        #pragma unroll
        for (int c2 = 0; c2 < 4; ++c2)
            m = fmaxf(m, fmaxf(fmaxf(v[c2].x, v[c2].y), fmaxf(v[c2].z, v[c2].w)));
        m = fmaxf(m, __shfl_xor(m, 1, 64));
        m = fmaxf(m, __shfl_xor(m, 2, 64));
        float lsum = 0.f;
        #pragma unroll
        for (int c2 = 0; c2 < 4; ++c2) {
            v[c2].x = __expf(v[c2].x - m); v[c2].y = __expf(v[c2].y - m);
            v[c2].z = __expf(v[c2].z - m); v[c2].w = __expf(v[c2].w - m);
            lsum += (v[c2].x + v[c2].y) + (v[c2].z + v[c2].w);
        }
        #pragma unroll
        for (int c2 = 0; c2 < 4; ++c2) S4[tok * 17 + q * 4 + c2] = v[c2];
        lsum += __shfl_xor(lsum, 1, 64);
        lsum += __shfl_xor(lsum, 2, 64);
        if (q == 0) recip[tok] = 1.0f / lsum;
    }
    __syncthreads();

    // ---- SEL (one wave, thread-per-token) + pi partials (other 7 waves) ----
    const int selw = blockIdx.x & 7;
    if (wave == selw) {
        const int tok = lane;
        const int tok_g = tok_base + tok;
        float val[9]; int idx[9];
        #pragma unroll
        for (int r = 0; r < 9; ++r) { val[r] = -1.f; idx[r] = 0; }
        #pragma unroll
        for (int c2 = 0; c2 < 16; ++c2) {
            f4 v = S4[tok * 17 + c2];
            float e4[4] = {v.x, v.y, v.z, v.w};
            #pragma unroll
            for (int u = 0; u < 4; ++u) {
                float cv = e4[u]; int ci = c2 * 4 + u;
                #pragma unroll
                for (int r = 0; r < 9; ++r) {
                    const bool g = cv > val[r];    // strict: stream order = stable ties
                    const float tv = val[r]; const int ti = idx[r];
                    val[r] = g ? cv : tv;  idx[r] = g ? ci : ti;
                    cv = g ? tv : cv;      ci = g ? ti : ci;
                }
            }
        }
        const float s8 = ((val[0] + val[1]) + (val[2] + val[3]))
                       + ((val[4] + val[5]) + (val[6] + val[7]));
        const float wsum = s8 + 1e-20f;
        f4* out4 = (f4*)out;
        f4 o;
        o.x = (float)idx[0]; o.y = (float)idx[1]; o.z = (float)idx[2]; o.w = (float)idx[3];
        out4[(size_t)tok_g * 2] = o;
        o.x = (float)idx[4]; o.y = (float)idx[5]; o.z = (float)idx[6]; o.w = (float)idx[7];
        out4[(size_t)tok_g * 2 + 1] = o;
        const size_t wb = (size_t)n_tokens * 2;
        o.x = val[0] / wsum; o.y = val[1] / wsum; o.z = val[2] / wsum; o.w = val[3] / wsum;
        out4[wb + (size_t)tok_g * 2] = o;
        o.x = val[4] / wsum; o.y = val[5] / wsum; o.z = val[6] / wsum; o.w = val[7] / wsum;
        out4[wb + (size_t)tok_g * 2 + 1] = o;
        #pragma unroll
        for (int r = 0; r < 8; ++r) atomicAdd(&hist[idx[r]], 1.0f);
        float ming = 1e30f;
        #pragma unroll
        for (int r = 0; r < 8; ++r)
            ming = fminf(ming, (val[r] - val[r + 1]) / fmaxf(val[r], 1e-30f));
        if (ming < THETA) {
            unsigned int pos = atomicAdd(risk_cnt, 1u);
            if (pos < risk_cap) risk_list[pos] = (unsigned int)tok_g;
        }
    } else {
        const int sev = ((wave - selw) & 7) - 1;          // 0..6
        const int e = lane;
        const int t0 = sev * 9;
        const int t1 = (sev == 6) ? 64 : (t0 + 9);
        float part = 0.f;
        for (int tok = t0; tok < t1; ++tok)
            part = fmaf(S[tok * 68 + e], recip[tok], part);
        pi7[sev * 64 + e] = part;
    }
    __syncthreads();
    // ---- 8-replica accumulators: atomic contention / 8 ----
    const int rep = (blockIdx.x & 7) << 6;
    if (t < 64) {
        const float p = ((pi7[t] + pi7[64 + t]) + (pi7[128 + t] + pi7[192 + t]))
                      + ((pi7[256 + t] + pi7[320 + t]) + pi7[384 + t]);
        atomicAdd(&pi_ws[rep + t], p);
    } else if (t < 128) {
        atomicAdd(&ce_ws[rep + (t - 64)], hist[t - 64]);
    }
}

// =====================================================================
// Pass B: fp64 recompute of risky tokens (exact ranking); block 0 also
// finalizes the aux loss (sums the 8 pi/ce replicas).
// =====================================================================
__global__ __launch_bounds__(256)
void gate_fixup(const float* __restrict__ hs, const float* __restrict__ wt,
                float* __restrict__ out, const unsigned int* __restrict__ risk_cnt,
                const unsigned int* __restrict__ risk_list, unsigned int risk_cap,
                int n_tokens, const float* __restrict__ pi_ws,
                const float* __restrict__ ce_ws) {
    __shared__ float hrow[H];
    __shared__ double red[256];
    const int t = threadIdx.x;

    if (blockIdx.x == 0 && t < 64) {              // aux loss (wave 0 only)
        double pi = 0.0, ce = 0.0;
        #pragma unroll
        for (int rp = 0; rp < 8; ++rp) {
            pi += (double)pi_ws[rp * 64 + t];
            ce += (double)ce_ws[rp * 64 + t];
        }
        pi /= (double)n_tokens;
        ce /= ((double)n_tokens * 8.0);
        double term = pi * ce * 64.0;
        #pragma unroll
        for (int off = 32; off > 0; off >>= 1) term += __shfl_xor(term, off, 64);
        if (t == 0) out[(size_t)n_tokens * 16] = (float)(term * 0.01);
    }

    unsigned int cnt = *risk_cnt;
    if (cnt > risk_cap) cnt = risk_cap;

    for (unsigned int u = blockIdx.x; u < cnt; u += gridDim.x) {
        const int tok = (int)risk_list[u];
        ((float4*)hrow)[t] = ((const float4*)(hs + (size_t)tok * H))[t];
        __syncthreads();

        const int e = t >> 2, sl = t & 3;
        const float4* wp = (const float4*)wt + (size_t)e * 256;
        const float4* hp = (const float4*)hrow;
        double acc = 0.0;
        #pragma unroll 8
        for (int k4 = 0; k4 < 64; ++k4) {
            float4 wv = wp[k4 * 4 + sl];
            float4 hv = hp[k4 * 4 + sl];
            acc = fma((double)wv.x, (double)hv.x, acc);
            acc = fma((double)wv.y, (double)hv.y, acc);
            acc = fma((double)wv.z, (double)hv.z, acc);
            acc = fma((double)wv.w, (double)hv.w, acc);
        }
        red[t] = acc;
        __syncthreads();

        if (t < 64) {
            const int lane = t;
            double lg = red[t * 4] + red[t * 4 + 1] + red[t * 4 + 2] + red[t * 4 + 3];
            double m = lg;
            #pragma unroll
            for (int off = 32; off > 0; off >>= 1) {
                double o = __shfl_xor(m, off, 64);
                m = (o > m) ? o : m;
            }
            const double p = exp(lg - m);
            double v = lg, psum = 0.0, mypv = 0.0;
            int myidx = 0;
            for (int r = 0; r < 8; ++r) {
                double bv = v; int bi = lane;
                #pragma unroll
                for (int off = 32; off > 0; off >>= 1) {
                    double ov = __shfl_xor(bv, off, 64);
                    int    oi = __shfl_xor(bi, off, 64);
                    if (ov > bv || (ov == bv && oi < bi)) { bv = ov; bi = oi; }
                }
                double pw = __shfl(p, bi, 64);
                psum += pw;
                if (lane == r) { myidx = bi; mypv = pw; }
                if (lane == bi) v = -1e300;
            }
            const double wsum = psum + 1e-20;
            if (lane < 8) {
                out[(size_t)tok * 8 + lane] = (float)myidx;
                out[(size_t)n_tokens * 8 + (size_t)tok * 8 + lane] = (float)(mypv / wsum);
            }
        }
        __syncthreads();
    }
}

extern "C" void kernel_launch(void* const* d_in, const int* in_sizes, int n_in,
                              void* d_out, int out_size, void* d_ws, size_t ws_size,
                              hipStream_t stream) {
    const float* hs = (const float*)d_in[0];
    const float* wt = (const float*)d_in[1];
    float* out = (float*)d_out;
    const int n_tokens = in_sizes[0] / H;         // 32768

    // ws layout: pi[8][64] @0 (2048B), ce[8][64] @2048, risk_cnt @4096,
    //            risk_list @4608
    float* pi_ws = (float*)d_ws;
    float* ce_ws = (float*)((char*)d_ws + 2048);
    unsigned int* risk_cnt  = (unsigned int*)((char*)d_ws + 4096);
    unsigned int* risk_list = (unsigned int*)((char*)d_ws + 4608);
    unsigned int risk_cap = (unsigned int)((ws_size > 4608 ? (ws_size - 4608) : 0) / 4);
    if (risk_cap > (unsigned int)n_tokens) risk_cap = (unsigned int)n_tokens;

    size_t zbytes = ws_size < 4608 ? ws_size : 4608;
    hipMemsetAsync(d_ws, 0, zbytes, stream);

    gate_main<<<n_tokens / BT, 512, 0, stream>>>(hs, wt, out, pi_ws, ce_ws,
                                                 risk_cnt, risk_list, risk_cap, n_tokens);
    gate_fixup<<<256, 256, 0, stream>>>(hs, wt, out, risk_cnt, risk_list, risk_cap,
                                        n_tokens, pi_ws, ce_ws);
}

// Round 5
// 237.383 us; speedup vs baseline: 1.1573x; 1.0047x over previous
//
#include <hip/hip_runtime.h>

#define H 1024
#define E 64
#define BT 32
#define THETA 1e-4f    // relative p-gap risk threshold (~3-6x margin over split-bf16 error tail)

typedef __attribute__((ext_vector_type(4))) float f4;
typedef __attribute__((ext_vector_type(16))) float f32x16;
typedef __bf16 bf16x8 __attribute__((ext_vector_type(8)));
typedef unsigned int u32;
typedef __attribute__((ext_vector_type(4))) u32 u32x4;

__device__ __forceinline__ u32 cvtpk_bf16(float a, float b) {
    u32 r;
    asm("v_cvt_pk_bf16_f32 %0, %1, %2" : "=v"(r) : "v"(a), "v"(b));
    return r;
}
__device__ __forceinline__ float asfloat(u32 u) { union { u32 u; float f; } c; c.u = u; return c.f; }

// split 8 fp32 (k-ascending: a.xyzw, b.xyzw) into packed bf16-hi (RNE) and bf16-lo residual
__device__ __forceinline__ void split8(f4 a, f4 b, u32x4& hi, u32x4& lo) {
    float x0[4] = {a.x, a.z, b.x, b.z};
    float x1[4] = {a.y, a.w, b.y, b.w};
    #pragma unroll
    for (int i = 0; i < 4; ++i) {
        u32 h = cvtpk_bf16(x0[i], x1[i]);
        float r0 = x0[i] - asfloat(h << 16);
        float r1 = x1[i] - asfloat(h & 0xFFFF0000u);
        hi[i] = h;
        lo[i] = cvtpk_bf16(r0, r1);
    }
}

// async global->LDS, 16B per lane; LDS dest = wave-uniform base + lane*16
__device__ __forceinline__ void async16(const void* g, void* l) {
    __builtin_amdgcn_global_load_lds(
        (const __attribute__((address_space(1))) unsigned int*)g,
        (__attribute__((address_space(3))) unsigned int*)l,
        16, 0, 0);
}

// =====================================================================
// Pass A (round 5): 32 tokens x 64 experts per block, 256 threads =
// 4 waves (2 expert-halves x 2 K-halves) -> 1024 blocks = 4 independent
// barrier domains per CU (phase diversity breaks the 8-wave convoy).
// K-chunks of 32; THREE 12 KB LDS buffers, prefetch depth 2, counted
// vmcnt(3) (never drains mid-loop); fragment REGISTER pipeline 1 chunk
// ahead so ds_read latency hides under a full iteration of compute.
// Math unchanged from round 4: source-side XOR swizzle (f4-slot
// j ^= row&7), split-bf16 MFMA (hi*hi -> acc0, hi*lo + lo*hi -> acc1).
// LDS byte map: buf b at b*12288: A[32][32]f32 @0 (4 KB), B[64][32]f32
// @4096 (8 KB). tail (reuses bufs): S[32][68] @f0, P2[2][32][32] @f2176,
// recip @f4224, hist @f4256, pi3[3][64] @f4320
// =====================================================================
__global__ __launch_bounds__(256, 4)
void gate_main(const float* __restrict__ hs, const float* __restrict__ wt,
               float* __restrict__ out, float* __restrict__ pi_ws,
               float* __restrict__ ce_ws, unsigned int* __restrict__ risk_cnt,
               unsigned int* __restrict__ risk_list, unsigned int risk_cap,
               int n_tokens) {
    __shared__ float smem[9216];                  // 36 KB
    const int t = threadIdx.x;
    const int wave = t >> 6, lane = t & 63;
    const int tok_base = blockIdx.x * BT;
    char* sb = (char*)smem;

    // ---- staging constants (3 loads/thread/chunk: 1 A + 2 B) ----
    const int arow_s  = t >> 3;                   // 0..31
    const int aslot_s = (t & 7) ^ (arow_s & 7);
    const float* gA  = hs + (size_t)(tok_base + arow_s) * H + aslot_s * 4;
    const int brow1  = t >> 3;                    // 0..31
    const int bslot1 = (t & 7) ^ (brow1 & 7);
    const float* gB1 = wt + (size_t)brow1 * H + bslot1 * 4;
    const int brow2  = (t + 256) >> 3;            // 32..63
    const int bslot2 = (t & 7) ^ (brow2 & 7);
    const float* gB2 = wt + (size_t)brow2 * H + bslot2 * 4;
    const int dA  = t * 16;
    const int dB1 = 4096 + t * 16;
    const int dB2 = 8192 + t * 16;

    // ---- mfma constants: wave -> expert-half (e2) x K-half (kh2) ----
    const int lr = lane & 31, kh = lane >> 5;
    const int e2 = wave & 1, kh2 = wave >> 1;
    const int s0 = kh2 * 4 + kh * 2;              // even f4 slot of this lane's 8 k
    const int arow = lr;
    const int brow = e2 * 32 + lr;
    const int aoff0 = arow * 128 + ((s0 ^ (arow & 7)) << 4);
    const int aoff1 = arow * 128 + (((s0 + 1) ^ (arow & 7)) << 4);
    const int boff0 = 4096 + brow * 128 + ((s0 ^ (brow & 7)) << 4);
    const int boff1 = 4096 + brow * 128 + (((s0 + 1) ^ (brow & 7)) << 4);

    f32x16 acc0, acc1;
    #pragma unroll
    for (int i = 0; i < 16; ++i) { acc0[i] = 0.f; acc1[i] = 0.f; }

    auto stage = [&](int c) {
        char* bb = sb + (c % 3) * 12288;
        const int co = c * 32;
        async16(gA  + co, bb + dA);
        async16(gB1 + co, bb + dB1);
        async16(gB2 + co, bb + dB2);
    };

    f4 fa0[2], fa1[2], fb0[2], fb1[2];            // 1-ahead fragment regs
    auto fragread = [&](int c, int p) {
        const char* cb = sb + (c % 3) * 12288;
        fa0[p] = *(const f4*)(cb + aoff0);
        fa1[p] = *(const f4*)(cb + aoff1);
        fb0[p] = *(const f4*)(cb + boff0);
        fb1[p] = *(const f4*)(cb + boff1);
    };
    auto computeF = [&](int p) {
        u32x4 ahp, alp, bhp, blp;
        split8(fa0[p], fa1[p], ahp, alp);
        split8(fb0[p], fb1[p], bhp, blp);
        const bf16x8 ah = __builtin_bit_cast(bf16x8, ahp);
        const bf16x8 al = __builtin_bit_cast(bf16x8, alp);
        const bf16x8 bh = __builtin_bit_cast(bf16x8, bhp);
        const bf16x8 bl = __builtin_bit_cast(bf16x8, blp);
        __builtin_amdgcn_s_setprio(1);
        acc0 = __builtin_amdgcn_mfma_f32_32x32x16_bf16(ah, bh, acc0, 0, 0, 0);
        acc1 = __builtin_amdgcn_mfma_f32_32x32x16_bf16(ah, bl, acc1, 0, 0, 0);
        acc1 = __builtin_amdgcn_mfma_f32_32x32x16_bf16(al, bh, acc1, 0, 0, 0);
        __builtin_amdgcn_s_setprio(0);
    };

    // ---- prologue: 2 chunks in flight (6 loads/thread)
    stage(0); stage(1);
    asm volatile("s_waitcnt vmcnt(3)" ::: "memory");   // chunk 0 retired
    __builtin_amdgcn_s_barrier();
    fragread(0, 0);
    // ---- main loop: compute c from regs, read c+1 frags, stage c+2
    #pragma unroll 2
    for (int c = 0; c < 32; ++c) {
        if (c + 2 < 32) stage(c + 2);             // overwrites buf (c-1)%3: its frag
                                                  // reads issued iter c-2, consumed iter c-1
        if (c + 1 < 32) {
            if (c + 1 < 31) { asm volatile("s_waitcnt vmcnt(3)" ::: "memory"); }
            else            { asm volatile("s_waitcnt vmcnt(0)" ::: "memory"); }
            __builtin_amdgcn_s_barrier();         // publish chunk c+1
            fragread(c + 1, (c + 1) & 1);
        }
        computeF(c & 1);                          // frag(c) read last iter: latency hidden
    }
    __syncthreads();                              // buffers dead from here

    float* S = smem;                              // [32][68]
    f4* S4 = (f4*)smem;
    float* P2    = smem + 2176;                   // [2][32][32] K-half partials
    float* recip = smem + 4224;                   // [32]
    float* hist  = smem + 4256;                   // [64]
    float* pi3   = smem + 4320;                   // [3][64]

    // ---- combine K-half partials, write logits S[32][68] ----
    {
        float vs[16];
        #pragma unroll
        for (int i = 0; i < 16; ++i) vs[i] = acc0[i] + acc1[i];
        if (kh2) {
            #pragma unroll
            for (int gq = 0; gq < 4; ++gq)
                #pragma unroll
                for (int qq = 0; qq < 4; ++qq)
                    P2[e2 * 1024 + (qq + gq * 8 + kh * 4) * 32 + lr] = vs[gq * 4 + qq];
        }
        if (t < 64) hist[t] = 0.f;
        __syncthreads();
        if (!kh2) {
            #pragma unroll
            for (int gq = 0; gq < 4; ++gq)
                #pragma unroll
                for (int qq = 0; qq < 4; ++qq) {
                    const int row = qq + gq * 8 + kh * 4;   // C/D layout (m74/m101)
                    S[row * 68 + e2 * 32 + lr] =
                        vs[gq * 4 + qq] + P2[e2 * 1024 + row * 32 + lr];
                }
        }
    }
    __syncthreads();

    // ---- p = exp(l - m) in-place, 4 threads per token (threads 0..127) ----
    if (t < 128) {
        const int tok = t >> 2, q = t & 3;
        f4 v[4];
        #pragma unroll
        for (int c2 = 0; c2 < 4; ++c2) v[c2] = S4[tok * 17 + q * 4 + c2];
        float m = v[0].x;
        #pragma unroll
        for (int c2 = 0; c2 < 4; ++c2)
            m = fmaxf(m, fmaxf(fmaxf(v[c2].x, v[c2].y), fmaxf(v[c2].z, v[c2].w)));
        m = fmaxf(m, __shfl_xor(m, 1, 64));
        m = fmaxf(m, __shfl_xor(m, 2, 64));
        float lsum = 0.f;
        #pragma unroll
        for (int c2 = 0; c2 < 4; ++c2) {
            v[c2].x = __expf(v[c2].x - m); v[c2].y = __expf(v[c2].y - m);
            v[c2].z = __expf(v[c2].z - m); v[c2].w = __expf(v[c2].w - m);
            lsum += (v[c2].x + v[c2].y) + (v[c2].z + v[c2].w);
        }
        #pragma unroll
        for (int c2 = 0; c2 < 4; ++c2) S4[tok * 17 + q * 4 + c2] = v[c2];
        lsum += __shfl_xor(lsum, 1, 64);
        lsum += __shfl_xor(lsum, 2, 64);
        if (q == 0) recip[tok] = 1.0f / lsum;
    }
    __syncthreads();

    // ---- SEL (one wave, lanes 0..31 = tokens) + pi partials (3 waves) ----
    const int selw = blockIdx.x & 3;
    if (wave == selw) {
        if (lane < 32) {
            const int tok = lane;
            const int tok_g = tok_base + tok;
            float val[9]; int idx[9];
            #pragma unroll
            for (int r = 0; r < 9; ++r) { val[r] = -1.f; idx[r] = 0; }
            #pragma unroll
            for (int c2 = 0; c2 < 16; ++c2) {
                f4 v = S4[tok * 17 + c2];
                float e4[4] = {v.x, v.y, v.z, v.w};
                #pragma unroll
                for (int u = 0; u < 4; ++u) {
                    float cv = e4[u]; int ci = c2 * 4 + u;
                    #pragma unroll
                    for (int r = 0; r < 9; ++r) {
                        const bool g = cv > val[r];    // strict: stable ties
                        const float tv = val[r]; const int ti = idx[r];
                        val[r] = g ? cv : tv;  idx[r] = g ? ci : ti;
                        cv = g ? tv : cv;      ci = g ? ti : ci;
                    }
                }
            }
            const float s8 = ((val[0] + val[1]) + (val[2] + val[3]))
                           + ((val[4] + val[5]) + (val[6] + val[7]));
            const float wsum = s8 + 1e-20f;
            f4* out4 = (f4*)out;
            f4 o;
            o.x = (float)idx[0]; o.y = (float)idx[1]; o.z = (float)idx[2]; o.w = (float)idx[3];
            out4[(size_t)tok_g * 2] = o;
            o.x = (float)idx[4]; o.y = (float)idx[5]; o.z = (float)idx[6]; o.w = (float)idx[7];
            out4[(size_t)tok_g * 2 + 1] = o;
            const size_t wb = (size_t)n_tokens * 2;
            o.x = val[0] / wsum; o.y = val[1] / wsum; o.z = val[2] / wsum; o.w = val[3] / wsum;
            out4[wb + (size_t)tok_g * 2] = o;
            o.x = val[4] / wsum; o.y = val[5] / wsum; o.z = val[6] / wsum; o.w = val[7] / wsum;
            out4[wb + (size_t)tok_g * 2 + 1] = o;
            #pragma unroll
            for (int r = 0; r < 8; ++r) atomicAdd(&hist[idx[r]], 1.0f);
            float ming = 1e30f;
            #pragma unroll
            for (int r = 0; r < 8; ++r)
                ming = fminf(ming, (val[r] - val[r + 1]) / fmaxf(val[r], 1e-30f));
            if (ming < THETA) {
                unsigned int pos = atomicAdd(risk_cnt, 1u);
                if (pos < risk_cap) risk_list[pos] = (unsigned int)tok_g;
            }
        }
    } else {
        const int third = ((wave - selw) & 3) - 1;        // 0..2
        const int e = lane;
        const int t0 = third * 11;
        const int t1 = (third == 2) ? 32 : (t0 + 11);
        float part = 0.f;
        for (int tok = t0; tok < t1; ++tok)
            part = fmaf(S[tok * 68 + e], recip[tok], part);
        pi3[third * 64 + e] = part;
    }
    __syncthreads();
    // ---- 8-replica accumulators: atomic contention / 8 ----
    const int rep = (blockIdx.x & 7) << 6;
    if (t < 64) {
        atomicAdd(&pi_ws[rep + t], pi3[t] + pi3[64 + t] + pi3[128 + t]);
    } else if (t < 128) {
        atomicAdd(&ce_ws[rep + (t - 64)], hist[t - 64]);
    }
}

// =====================================================================
// Pass B: fp64 recompute of risky tokens (exact ranking); block 0 also
// finalizes the aux loss (sums the 8 pi/ce replicas).
// =====================================================================
__global__ __launch_bounds__(256)
void gate_fixup(const float* __restrict__ hs, const float* __restrict__ wt,
                float* __restrict__ out, const unsigned int* __restrict__ risk_cnt,
                const unsigned int* __restrict__ risk_list, unsigned int risk_cap,
                int n_tokens, const float* __restrict__ pi_ws,
                const float* __restrict__ ce_ws) {
    __shared__ float hrow[H];
    __shared__ double red[256];
    const int t = threadIdx.x;

    if (blockIdx.x == 0 && t < 64) {              // aux loss (wave 0 only)
        double pi = 0.0, ce = 0.0;
        #pragma unroll
        for (int rp = 0; rp < 8; ++rp) {
            pi += (double)pi_ws[rp * 64 + t];
            ce += (double)ce_ws[rp * 64 + t];
        }
        pi /= (double)n_tokens;
        ce /= ((double)n_tokens * 8.0);
        double term = pi * ce * 64.0;
        #pragma unroll
        for (int off = 32; off > 0; off >>= 1) term += __shfl_xor(term, off, 64);
        if (t == 0) out[(size_t)n_tokens * 16] = (float)(term * 0.01);
    }

    unsigned int cnt = *risk_cnt;
    if (cnt > risk_cap) cnt = risk_cap;

    for (unsigned int u = blockIdx.x; u < cnt; u += gridDim.x) {
        const int tok = (int)risk_list[u];
        ((float4*)hrow)[t] = ((const float4*)(hs + (size_t)tok * H))[t];
        __syncthreads();

        const int e = t >> 2, sl = t & 3;
        const float4* wp = (const float4*)wt + (size_t)e * 256;
        const float4* hp = (const float4*)hrow;
        double acc = 0.0;
        #pragma unroll 8
        for (int k4 = 0; k4 < 64; ++k4) {
            float4 wv = wp[k4 * 4 + sl];
            float4 hv = hp[k4 * 4 + sl];
            acc = fma((double)wv.x, (double)hv.x, acc);
            acc = fma((double)wv.y, (double)hv.y, acc);
            acc = fma((double)wv.z, (double)hv.z, acc);
            acc = fma((double)wv.w, (double)hv.w, acc);
        }
        red[t] = acc;
        __syncthreads();

        if (t < 64) {
            const int lane = t;
            double lg = red[t * 4] + red[t * 4 + 1] + red[t * 4 + 2] + red[t * 4 + 3];
            double m = lg;
            #pragma unroll
            for (int off = 32; off > 0; off >>= 1) {
                double o = __shfl_xor(m, off, 64);
                m = (o > m) ? o : m;
            }
            const double p = exp(lg - m);
            double v = lg, psum = 0.0, mypv = 0.0;
            int myidx = 0;
            for (int r = 0; r < 8; ++r) {
                double bv = v; int bi = lane;
                #pragma unroll
                for (int off = 32; off > 0; off >>= 1) {
                    double ov = __shfl_xor(bv, off, 64);
                    int    oi = __shfl_xor(bi, off, 64);
                    if (ov > bv || (ov == bv && oi < bi)) { bv = ov; bi = oi; }
                }
                double pw = __shfl(p, bi, 64);
                psum += pw;
                if (lane == r) { myidx = bi; mypv = pw; }
                if (lane == bi) v = -1e300;
            }
            const double wsum = psum + 1e-20;
            if (lane < 8) {
                out[(size_t)tok * 8 + lane] = (float)myidx;
                out[(size_t)n_tokens * 8 + (size_t)tok * 8 + lane] = (float)(mypv / wsum);
            }
        }
        __syncthreads();
    }
}

extern "C" void kernel_launch(void* const* d_in, const int* in_sizes, int n_in,
                              void* d_out, int out_size, void* d_ws, size_t ws_size,
                              hipStream_t stream) {
    const float* hs = (const float*)d_in[0];
    const float* wt = (const float*)d_in[1];
    float* out = (float*)d_out;
    const int n_tokens = in_sizes[0] / H;         // 32768

    // ws layout: pi[8][64] @0 (2048B), ce[8][64] @2048, risk_cnt @4096,
    //            risk_list @4608
    float* pi_ws = (float*)d_ws;
    float* ce_ws = (float*)((char*)d_ws + 2048);
    unsigned int* risk_cnt  = (unsigned int*)((char*)d_ws + 4096);
    unsigned int* risk_list = (unsigned int*)((char*)d_ws + 4608);
    unsigned int risk_cap = (unsigned int)((ws_size > 4608 ? (ws_size - 4608) : 0) / 4);
    if (risk_cap > (unsigned int)n_tokens) risk_cap = (unsigned int)n_tokens;

    size_t zbytes = ws_size < 4608 ? ws_size : 4608;
    hipMemsetAsync(d_ws, 0, zbytes, stream);

    gate_main<<<n_tokens / BT, 256, 0, stream>>>(hs, wt, out, pi_ws, ce_ws,
                                                 risk_cnt, risk_list, risk_cap, n_tokens);
    gate_fixup<<<256, 256, 0, stream>>>(hs, wt, out, risk_cnt, risk_list, risk_cap,
                                        n_tokens, pi_ws, ce_ws);
}